// Round 13
// baseline (38.975 us; speedup 1.0000x reference)
//
#include <hip/hip_runtime.h>
#include <math.h>

// Problem constants
constexpr int NT = 32;     // components
constexpr int ND = 1024;   // dim
constexpr int NB = 4096;   // batch
constexpr int TROWS = 8;         // rows per tile
constexpr int NTILE = 2;         // tiles per k_main block (pipelined)
constexpr int NBLK_MAIN = NB / (TROWS * NTILE);  // 256
constexpr int NPART = NB / TROWS;                // 512 Pg/Pp slots

typedef float f2 __attribute__((ext_vector_type(2)));

// Workspace layout (float offsets)
//  ivc : [256][32][4] chunk-major inv_var            @ 0       (32768)
//  m2c : [256][32][4] chunk-major (-2*mu*inv_var)    @ 32768   (32768)
//  c2  : [32]  sum(mu^2*inv_var)                     @ 65536   (32)
//  klg : [B][T]                                      @ 65600   (131072)
//  lpi : [B][T]                                      @ 196672  (131072)
//  Pg  : [512][32] per-tile partial sum klg          @ 327744  (16384)
//  Pp  : [512][32] per-tile partial sum lpi          @ 344128  (16384)
constexpr int OFF_M2C = 32768;
constexpr int OFF_C2  = 65536;
constexpr int OFF_KLG = 65600;
constexpr int OFF_LPI = 196672;
constexpr int OFF_PG  = 327744;
constexpr int OFF_PP  = 344128;

// ---------------------------------------------------------------------------
// Kernel A: per-component stats + zero out[0].
// grid = 32 (one block per component t), block = 256.
// ---------------------------------------------------------------------------
__global__ __launch_bounds__(256) void k_stats(const float* __restrict__ mu,
                                               const float* __restrict__ rho,
                                               float* __restrict__ ws,
                                               float* __restrict__ out) {
  float* ivc = ws;
  float* m2c = ws + OFF_M2C;
  float* c2  = ws + OFF_C2;

  const int t = blockIdx.x;
  const int c = threadIdx.x;  // chunk index 0..255 (covers d = 4c..4c+3)

  float4 mu4  = reinterpret_cast<const float4*>(mu  + t * ND)[c];
  float4 rho4 = reinterpret_cast<const float4*>(rho + t * ND)[c];

  float rr[4] = {rho4.x, rho4.y, rho4.z, rho4.w};
  float mm[4] = {mu4.x,  mu4.y,  mu4.z,  mu4.w};
  float iv[4], m2[4];
  float c2p = 0.0f;
#pragma unroll
  for (int j = 0; j < 4; ++j) {
    float sd  = log1pf(expf(rr[j]));   // softplus
    float ivv = 1.0f / (sd * sd);
    iv[j] = ivv;
    m2[j] = -2.0f * mm[j] * ivv;
    c2p  += mm[j] * mm[j] * ivv;
  }
  float4 iv4 = {iv[0], iv[1], iv[2], iv[3]};
  float4 m24 = {m2[0], m2[1], m2[2], m2[3]};
  reinterpret_cast<float4*>(ivc)[c * NT + t] = iv4;   // chunk-major
  reinterpret_cast<float4*>(m2c)[c * NT + t] = m24;

#pragma unroll
  for (int m = 32; m >= 1; m >>= 1) c2p += __shfl_xor(c2p, m, 64);
  __shared__ float red[4];
  const int wave = threadIdx.x >> 6, lane = threadIdx.x & 63;
  if (lane == 0) red[wave] = c2p;
  __syncthreads();
  if (threadIdx.x == 0) {
    c2[t] = red[0] + red[1] + red[2] + red[3];
    if (t == 0) out[0] = 0.0f;   // must re-zero every launch (graph replays)
  }
}

// ---------------------------------------------------------------------------
// Tile compute: r8's loop with packed f2 FMA (32 VALU/iter vs 64 scalar).
// Wave q owns d-eighth; lane (h,t). Reads xsb (LDS broadcast) + ivc/m2c (L2).
// Writes part[q][r][t].
// ---------------------------------------------------------------------------
__device__ __forceinline__ void compute_tile(const float* __restrict__ xsb,
                                             const float* __restrict__ ivc,
                                             const float* __restrict__ m2c,
                                             float (*part)[8][32],
                                             int q, int h, int t) {
  const int c0 = q * 32 + h * 16;
  const float4* ivp = reinterpret_cast<const float4*>(ivc) + (size_t)c0 * NT + t;
  const float4* m2p = reinterpret_cast<const float4*>(m2c) + (size_t)c0 * NT + t;
  const float4* xs4 = reinterpret_cast<const float4*>(xsb) + c0;

  f2 a2[TROWS];
#pragma unroll
  for (int r = 0; r < TROWS; ++r) a2[r] = (f2){0.f, 0.f};

#pragma unroll 4
  for (int i = 0; i < 16; ++i) {
    float4 iv4 = ivp[(size_t)i * NT];
    float4 m24 = m2p[(size_t)i * NT];
    const f2 ivl = {iv4.x, iv4.y}, ivh = {iv4.z, iv4.w};
    const f2 ml  = {m24.x, m24.y}, mh  = {m24.z, m24.w};
#pragma unroll
    for (int r = 0; r < TROWS; ++r) {
      float4 xv = xs4[r * 256 + i];   // broadcast ds_read_b128
      const f2 xl = {xv.x, xv.y}, xh = {xv.z, xv.w};
      a2[r] = __builtin_elementwise_fma(xl, __builtin_elementwise_fma(xl, ivl, ml), a2[r]);
      a2[r] = __builtin_elementwise_fma(xh, __builtin_elementwise_fma(xh, ivh, mh), a2[r]);
    }
  }
#pragma unroll
  for (int r = 0; r < TROWS; ++r) {
    float s = a2[r].x + a2[r].y;
    s += __shfl_xor(s, 32, 64);     // combine the wave's two 64-d sub-halves
    if (h == 0) part[q][r][t] = s;
  }
}

// ---------------------------------------------------------------------------
// Tile epilogue (r8's, parameterized): quad -> kv; beta scan -> lp;
// klg/lpi stores; per-tile partial sums -> Pg/Pp (plain stores, no atomics).
// Contains block-wide barriers; call under uniform control flow.
// ---------------------------------------------------------------------------
__device__ __forceinline__ void epilogue_tile(int tid, int rowB, int slot,
                                              const float* __restrict__ beta,
                                              const float* __restrict__ c2,
                                              float (*part)[8][32],
                                              float* __restrict__ klg,
                                              float* __restrict__ lpi,
                                              float* __restrict__ Pg,
                                              float* __restrict__ Pp) {
  const int rr = tid >> 5, t2 = tid & 31;
  float kv = 0.f, lp = 0.f;
  if (tid < 256) {
    float quad = 0.f;
#pragma unroll
    for (int qq = 0; qq < 8; ++qq) quad += part[qq][rr][t2];
    // kl_gaussian = log_pdfs + entropy = D/2 - 0.5*quad (log_std_sum cancels)
    kv = 512.0f - 0.5f * (quad + c2[t2]);
    klg[(size_t)(rowB + rr) * NT + t2] = kv;

    // log_pi: exclusive prefix scan of log1p(-beta) within each 32-lane group
    const float b = beta[(size_t)(rowB + rr) * NT + t2];
    const float l1m = log1pf(-b);
    float s = l1m;
#pragma unroll
    for (int d = 1; d < 32; d <<= 1) {
      float v = __shfl_up(s, (unsigned)d, 32);
      if (t2 >= d) s += v;
    }
    lp = logf(b) + (s - l1m);   // exclusive prefix + log(beta)
    lpi[(size_t)(rowB + rr) * NT + t2] = lp;
  }
  __syncthreads();                 // all part reads done before reuse
  if (tid < 256) {
    part[0][rr][t2] = kv;          // reuse part as reduce scratch
    part[1][rr][t2] = lp;
  }
  __syncthreads();
  if (tid < 32) {
    float sg = 0.f, sp = 0.f;
#pragma unroll
    for (int r = 0; r < TROWS; ++r) { sg += part[0][r][tid]; sp += part[1][r][tid]; }
    Pg[(size_t)slot * NT + tid] = sg;
    Pp[(size_t)slot * NT + tid] = sp;
  }
}

// ---------------------------------------------------------------------------
// Kernel B v10: software-pipelined 2-tile GEMM (T14 async-stage split).
// grid = 256 blocks x 512 threads (8 waves). Block owns 16 rows = 2 tiles
// of 8, double-buffered xs (72 KB LDS total). T1's global loads issue right
// after the first barrier and fly under T0's whole compute -> T1 stage
// latency hidden. pk-f32 FMA halves VALU issue. Plain stores, no atomics.
// ---------------------------------------------------------------------------
__global__ __launch_bounds__(512) void k_main(const float* __restrict__ x,
                                              const float* __restrict__ beta,
                                              float* __restrict__ ws) {
  const float* ivc = ws;
  const float* m2c = ws + OFF_M2C;
  const float* c2  = ws + OFF_C2;
  float* klg = ws + OFF_KLG;
  float* lpi = ws + OFF_LPI;
  float* Pg  = ws + OFF_PG;
  float* Pp  = ws + OFF_PP;

  const int tid  = threadIdx.x;
  const int q    = tid >> 6;        // wave = d-eighth (0..7)
  const int lane = tid & 63;
  const int h = lane >> 5, t = lane & 31;
  const int row0 = blockIdx.x * (TROWS * NTILE);   // 16 rows per block

  __shared__ float xs0[TROWS * ND];     // 32 KB tile buffer 0
  __shared__ float xs1[TROWS * ND];     // 32 KB tile buffer 1
  __shared__ float part[8][TROWS][32];  // 8 KB

  const float4* xg4 = reinterpret_cast<const float4*>(x) + (size_t)row0 * 256;
  float4 st[4];

  // ---- Stage T0 ----
#pragma unroll
  for (int k = 0; k < 4; ++k) st[k] = xg4[k * 512 + tid];
  {
    float4* w = reinterpret_cast<float4*>(xs0);
#pragma unroll
    for (int k = 0; k < 4; ++k) w[k * 512 + tid] = st[k];
  }
  __syncthreads();

  // ---- Issue T1 loads (in flight during T0 compute) ----
#pragma unroll
  for (int k = 0; k < 4; ++k) st[k] = xg4[2048 + k * 512 + tid];  // rows +8

  // ---- Compute T0 ----
  compute_tile(xs0, ivc, m2c, part, q, h, t);

  // ---- Land T1 into the free buffer, one barrier covers part+xs1 ----
  {
    float4* w = reinterpret_cast<float4*>(xs1);
#pragma unroll
    for (int k = 0; k < 4; ++k) w[k * 512 + tid] = st[k];
  }
  __syncthreads();

  // ---- Epilogue T0 ----
  epilogue_tile(tid, row0, blockIdx.x * 2 + 0, beta, c2, part, klg, lpi, Pg, Pp);
  __syncthreads();   // protect part (epilogue reads) from T1 compute writes

  // ---- Compute T1 + epilogue T1 ----
  compute_tile(xs1, ivc, m2c, part, q, h, t);
  __syncthreads();
  epilogue_tile(tid, row0 + TROWS, blockIdx.x * 2 + 1, beta, c2, part, klg, lpi, Pg, Pp);
}

// ---------------------------------------------------------------------------
// Kernel D: redundant per-block reduce of Pg/Pp (no contended atomics), then
// mix, softmax over T, weighted mean.
// grid = 256, block = 512 (8 waves; 16 rows/block, one per 32-lane group)
// ---------------------------------------------------------------------------
__global__ __launch_bounds__(512) void k_final(const float* __restrict__ ws,
                                               float* __restrict__ out) {
  const float* klg = ws + OFF_KLG;
  const float* lpi = ws + OFF_LPI;
  const float* Pg  = ws + OFF_PG;
  const float* Pp  = ws + OFF_PP;

  const int tid  = threadIdx.x;
  const int wave = tid >> 6, lane = tid & 63;
  const int t = tid & 31;        // component
  const int g = tid >> 5;        // reduce group 0..15 / row-in-block

  __shared__ float ngF[32], npF[32];
  __shared__ float redG[8][32], redP[8][32];
  __shared__ float red[8];

  // ---- Prologue: reduce the 512 per-tile partials (redundant) ----
  {
    float sg = 0.f, sp = 0.f;
#pragma unroll 8
    for (int b = g; b < NPART; b += 16) {
      sg += Pg[(size_t)b * NT + t];
      sp += Pp[(size_t)b * NT + t];
    }
    sg += __shfl_xor(sg, 32, 64);
    sp += __shfl_xor(sp, 32, 64);
    if (lane < 32) { redG[wave][t] = sg; redP[wave][t] = sp; }
  }
  __syncthreads();
  if (tid < 32) {
    float ng = 0.f, np = 0.f;
#pragma unroll
    for (int w = 0; w < 8; ++w) { ng += redG[w][tid]; np += redP[w][tid]; }
    ngF[tid] = ng;
    npF[tid] = np;
  }
  __syncthreads();

  // ---- mix + softmax over T + weighted mean ----
  const int row = blockIdx.x * 16 + g;
  const float kg = klg[(size_t)row * NT + t];
  const float lp = lpi[(size_t)row * NT + t];
  const float ng = ngF[t], np = npF[t];
  const float mix  = np / (ng + np);
  const float klgm = mix * kg;
  const float kl   = klgm + (1.0f - mix) * lp;

  float m = kl;
#pragma unroll
  for (int mk = 16; mk >= 1; mk >>= 1) m = fmaxf(m, __shfl_xor(m, mk, 64));
  const float e = expf(kl - m);
  float num = e * klgm, den = e;
#pragma unroll
  for (int mk = 16; mk >= 1; mk >>= 1) {
    num += __shfl_xor(num, mk, 64);
    den += __shfl_xor(den, mk, 64);
  }
  float s = num / den;           // per-row sum_t phi*klgm (replicated in group)
  s += __shfl_xor(s, 32, 64);    // combine the wave's two rows

  if (lane == 0) red[wave] = s;
  __syncthreads();
  if (tid == 0) {
    float tot = 0.f;
#pragma unroll
    for (int w = 0; w < 8; ++w) tot += red[w];
    atomicAdd(out, tot * (1.0f / (float)NB));
  }
}

// ---------------------------------------------------------------------------
extern "C" void kernel_launch(void* const* d_in, const int* in_sizes, int n_in,
                              void* d_out, int out_size, void* d_ws, size_t ws_size,
                              hipStream_t stream) {
  const float* x    = (const float*)d_in[0];
  const float* mu   = (const float*)d_in[1];
  const float* rho  = (const float*)d_in[2];
  const float* beta = (const float*)d_in[3];
  float* out = (float*)d_out;
  float* ws  = (float*)d_ws;

  hipLaunchKernelGGL(k_stats, dim3(32),        dim3(256), 0, stream, mu, rho, ws, out);
  hipLaunchKernelGGL(k_main,  dim3(NBLK_MAIN), dim3(512), 0, stream, x, beta, ws);
  hipLaunchKernelGGL(k_final, dim3(256),       dim3(512), 0, stream, ws, out);
}

// Round 14
// 30.327 us; speedup vs baseline: 1.2852x; 1.2852x over previous
//
#include <hip/hip_runtime.h>
#include <math.h>

// Problem constants
constexpr int NT = 32;     // components
constexpr int ND = 1024;   // dim
constexpr int NB = 4096;   // batch
constexpr int NBLK_MAIN = 512;   // k_main grid

// Workspace layout (float offsets)
//  ivc : [256][32][4] chunk-major inv_var            @ 0       (32768)
//  m2c : [256][32][4] chunk-major (-2*mu*inv_var)    @ 32768   (32768)
//  c2  : [32]  sum(mu^2*inv_var)                     @ 65536   (32)
//  klg : [B][T]                                      @ 65600   (131072)
//  lpi : [B][T]                                      @ 196672  (131072)
//  Pg  : [512][32] per-block partial sum klg         @ 327744  (16384)
//  Pp  : [512][32] per-block partial sum lpi         @ 344128  (16384)
constexpr int OFF_M2C = 32768;
constexpr int OFF_C2  = 65536;
constexpr int OFF_KLG = 65600;
constexpr int OFF_LPI = 196672;
constexpr int OFF_PG  = 327744;
constexpr int OFF_PP  = 344128;

// ---------------------------------------------------------------------------
// Kernel A: per-component stats + zero out[0].
// grid = 32 (one block per component t), block = 256.
// ---------------------------------------------------------------------------
__global__ __launch_bounds__(256) void k_stats(const float* __restrict__ mu,
                                               const float* __restrict__ rho,
                                               float* __restrict__ ws,
                                               float* __restrict__ out) {
  float* ivc = ws;
  float* m2c = ws + OFF_M2C;
  float* c2  = ws + OFF_C2;

  const int t = blockIdx.x;
  const int c = threadIdx.x;  // chunk index 0..255 (covers d = 4c..4c+3)

  float4 mu4  = reinterpret_cast<const float4*>(mu  + t * ND)[c];
  float4 rho4 = reinterpret_cast<const float4*>(rho + t * ND)[c];

  float rr[4] = {rho4.x, rho4.y, rho4.z, rho4.w};
  float mm[4] = {mu4.x,  mu4.y,  mu4.z,  mu4.w};
  float iv[4], m2[4];
  float c2p = 0.0f;
#pragma unroll
  for (int j = 0; j < 4; ++j) {
    float sd  = log1pf(expf(rr[j]));   // softplus
    float ivv = 1.0f / (sd * sd);
    iv[j] = ivv;
    m2[j] = -2.0f * mm[j] * ivv;
    c2p  += mm[j] * mm[j] * ivv;
  }
  float4 iv4 = {iv[0], iv[1], iv[2], iv[3]};
  float4 m24 = {m2[0], m2[1], m2[2], m2[3]};
  reinterpret_cast<float4*>(ivc)[c * NT + t] = iv4;   // chunk-major
  reinterpret_cast<float4*>(m2c)[c * NT + t] = m24;

#pragma unroll
  for (int m = 32; m >= 1; m >>= 1) c2p += __shfl_xor(c2p, m, 64);
  __shared__ float red[4];
  const int wave = threadIdx.x >> 6, lane = threadIdx.x & 63;
  if (lane == 0) red[wave] = c2p;
  __syncthreads();
  if (threadIdx.x == 0) {
    c2[t] = red[0] + red[1] + red[2] + red[3];
    if (t == 0) out[0] = 0.0f;   // must re-zero every launch (graph replays)
  }
}

// ---------------------------------------------------------------------------
// Kernel B v11: barrier-free per-wave staging + iv/m2 prefetch.
// grid = 512 blocks x 512 threads (8 waves, 40 KB LDS, 4 blocks/CU -- the
// exact r8 shape). Wave q stages ITS OWN 8-row x 128-d x-slab (4 KB) into
// its own LDS region and reads only that region -> the block-wide stage
// __syncthreads() is eliminated; waves flow stage->compute independently
// (SIMD-mates pipeline each other's load waits). Iter-0 iv/m2 loads issue
// before the x-wait so the cold L3 miss hides under the stage drain.
// LDS region layout is load-order: float4 idx = k*64 + lane; the (row r,
// chunk cc) float4 lives at (cc>>3)*64 + r*8 + (cc&7).
// ---------------------------------------------------------------------------
__global__ __launch_bounds__(512, 4) void k_main(const float* __restrict__ x,
                                                 const float* __restrict__ beta,
                                                 float* __restrict__ ws) {
  const float* ivc = ws;
  const float* m2c = ws + OFF_M2C;
  const float* c2  = ws + OFF_C2;
  float* klg = ws + OFF_KLG;
  float* lpi = ws + OFF_LPI;
  float* Pg  = ws + OFF_PG;
  float* Pp  = ws + OFF_PP;

  const int tid  = threadIdx.x;
  const int q    = tid >> 6;        // wave = d-eighth (0..7)
  const int lane = tid & 63;
  const int h = lane >> 5, t = lane & 31;
  const int row0 = blockIdx.x * 8;

  __shared__ float xs[8 * 1024];    // 32 KB; wave q owns [q*1024, q*1024+1024)
  __shared__ float part[8][8][32];  // 8 KB

  // ---- Per-wave stage: lane (sr, sj) loads 4 float4 of rows 0..7 ----
  const float4* xg4 = reinterpret_cast<const float4*>(x);
  const int sr = lane >> 3;          // stage row 0..7
  const int sj = lane & 7;           // stage col-chunk base 0..7
  float4 st[4];
#pragma unroll
  for (int k = 0; k < 4; ++k)
    st[k] = xg4[(size_t)(row0 + sr) * 256 + q * 32 + sj + 8 * k];

  // ---- Prefetch iter-0 iv/m2 (cold miss hides under the x-load wait) ----
  const int c0 = q * 32 + h * 16;
  const float4* ivp = reinterpret_cast<const float4*>(ivc) + (size_t)c0 * NT + t;
  const float4* m2p = reinterpret_cast<const float4*>(m2c) + (size_t)c0 * NT + t;
  float4 iv0 = ivp[0];
  float4 m20 = m2p[0];

  // ---- Land x into this wave's LDS region (no block barrier needed) ----
  float4* xw = reinterpret_cast<float4*>(xs) + q * 256;
#pragma unroll
  for (int k = 0; k < 4; ++k) xw[k * 64 + lane] = st[k];

  // ---- FMA loop: x from own LDS region (broadcast), iv/m2 from L2 ----
  const float4* xr = reinterpret_cast<const float4*>(xs) + q * 256;
  float a[8] = {0.f, 0.f, 0.f, 0.f, 0.f, 0.f, 0.f, 0.f};

  // iter 0 (peeled, uses prefetched iv0/m20); chunk cc = h*16
  {
    const int cc = h * 16;
    const int xb = (cc >> 3) * 64 + (cc & 7);
#pragma unroll
    for (int r = 0; r < 8; ++r) {
      float4 xv = xr[xb + r * 8];   // broadcast ds_read_b128
      a[r] = fmaf(xv.x, fmaf(xv.x, iv0.x, m20.x), a[r]);
      a[r] = fmaf(xv.y, fmaf(xv.y, iv0.y, m20.y), a[r]);
      a[r] = fmaf(xv.z, fmaf(xv.z, iv0.z, m20.z), a[r]);
      a[r] = fmaf(xv.w, fmaf(xv.w, iv0.w, m20.w), a[r]);
    }
  }
#pragma unroll 5
  for (int i = 1; i < 16; ++i) {
    float4 iv4 = ivp[(size_t)i * NT];
    float4 m24 = m2p[(size_t)i * NT];
    const int cc = h * 16 + i;
    const int xb = (cc >> 3) * 64 + (cc & 7);
#pragma unroll
    for (int r = 0; r < 8; ++r) {
      float4 xv = xr[xb + r * 8];   // broadcast ds_read_b128
      a[r] = fmaf(xv.x, fmaf(xv.x, iv4.x, m24.x), a[r]);
      a[r] = fmaf(xv.y, fmaf(xv.y, iv4.y, m24.y), a[r]);
      a[r] = fmaf(xv.z, fmaf(xv.z, iv4.z, m24.z), a[r]);
      a[r] = fmaf(xv.w, fmaf(xv.w, iv4.w, m24.w), a[r]);
    }
  }
  // combine the two 64-d sub-halves within the wave
#pragma unroll
  for (int r = 0; r < 8; ++r) a[r] += __shfl_xor(a[r], 32, 64);

  if (h == 0) {
#pragma unroll
    for (int r = 0; r < 8; ++r) part[q][r][t] = a[r];
  }
  __syncthreads();   // the ONE barrier: all waves' part writes before epilogue

  // ---- Epilogue on first 4 waves: rr = row-in-block, t2 = component ----
  const int rr = tid >> 5, t2 = tid & 31;
  float kv = 0.f, lp = 0.f;
  if (tid < 256) {
    float quad = 0.f;
#pragma unroll
    for (int qq = 0; qq < 8; ++qq) quad += part[qq][rr][t2];
    // kl_gaussian = log_pdfs + entropy = D/2 - 0.5*quad (log_std_sum cancels)
    kv = 512.0f - 0.5f * (quad + c2[t2]);
    klg[(size_t)(row0 + rr) * NT + t2] = kv;

    // log_pi: exclusive prefix scan of log1p(-beta) within each 32-lane group
    const float b = beta[(size_t)(row0 + rr) * NT + t2];
    const float l1m = log1pf(-b);
    float s = l1m;
#pragma unroll
    for (int d = 1; d < 32; d <<= 1) {
      float v = __shfl_up(s, (unsigned)d, 32);
      if (t2 >= d) s += v;
    }
    lp = logf(b) + (s - l1m);   // exclusive prefix + log(beta)
    lpi[(size_t)(row0 + rr) * NT + t2] = lp;
  }
  __syncthreads();                 // all part reads done before reuse
  if (tid < 256) {
    part[0][rr][t2] = kv;          // reuse part as reduce scratch
    part[1][rr][t2] = lp;
  }
  __syncthreads();
  if (tid < 32) {
    float sg = 0.f, sp = 0.f;
#pragma unroll
    for (int r = 0; r < 8; ++r) { sg += part[0][r][tid]; sp += part[1][r][tid]; }
    // plain coalesced stores -- no atomics
    Pg[(size_t)blockIdx.x * NT + tid] = sg;
    Pp[(size_t)blockIdx.x * NT + tid] = sp;
  }
}

// ---------------------------------------------------------------------------
// Kernel D: redundant per-block reduce of Pg/Pp (no contended atomics), then
// mix, softmax over T, weighted mean.
// grid = 256, block = 512 (8 waves; 16 rows/block, one per 32-lane group)
// ---------------------------------------------------------------------------
__global__ __launch_bounds__(512) void k_final(const float* __restrict__ ws,
                                               float* __restrict__ out) {
  const float* klg = ws + OFF_KLG;
  const float* lpi = ws + OFF_LPI;
  const float* Pg  = ws + OFF_PG;
  const float* Pp  = ws + OFF_PP;

  const int tid  = threadIdx.x;
  const int wave = tid >> 6, lane = tid & 63;
  const int t = tid & 31;        // component
  const int g = tid >> 5;        // reduce group 0..15 / row-in-block

  __shared__ float ngF[32], npF[32];
  __shared__ float redG[8][32], redP[8][32];
  __shared__ float red[8];

  // ---- Prologue: reduce the 512 per-block partials (redundant) ----
  {
    float sg = 0.f, sp = 0.f;
#pragma unroll 8
    for (int b = g; b < NBLK_MAIN; b += 16) {
      sg += Pg[(size_t)b * NT + t];
      sp += Pp[(size_t)b * NT + t];
    }
    sg += __shfl_xor(sg, 32, 64);
    sp += __shfl_xor(sp, 32, 64);
    if (lane < 32) { redG[wave][t] = sg; redP[wave][t] = sp; }
  }
  __syncthreads();
  if (tid < 32) {
    float ng = 0.f, np = 0.f;
#pragma unroll
    for (int w = 0; w < 8; ++w) { ng += redG[w][tid]; np += redP[w][tid]; }
    ngF[tid] = ng;
    npF[tid] = np;
  }
  __syncthreads();

  // ---- mix + softmax over T + weighted mean ----
  const int row = blockIdx.x * 16 + g;
  const float kg = klg[(size_t)row * NT + t];
  const float lp = lpi[(size_t)row * NT + t];
  const float ng = ngF[t], np = npF[t];
  const float mix  = np / (ng + np);
  const float klgm = mix * kg;
  const float kl   = klgm + (1.0f - mix) * lp;

  float m = kl;
#pragma unroll
  for (int mk = 16; mk >= 1; mk >>= 1) m = fmaxf(m, __shfl_xor(m, mk, 64));
  const float e = expf(kl - m);
  float num = e * klgm, den = e;
#pragma unroll
  for (int mk = 16; mk >= 1; mk >>= 1) {
    num += __shfl_xor(num, mk, 64);
    den += __shfl_xor(den, mk, 64);
  }
  float s = num / den;           // per-row sum_t phi*klgm (replicated in group)
  s += __shfl_xor(s, 32, 64);    // combine the wave's two rows

  if (lane == 0) red[wave] = s;
  __syncthreads();
  if (tid == 0) {
    float tot = 0.f;
#pragma unroll
    for (int w = 0; w < 8; ++w) tot += red[w];
    atomicAdd(out, tot * (1.0f / (float)NB));
  }
}

// ---------------------------------------------------------------------------
extern "C" void kernel_launch(void* const* d_in, const int* in_sizes, int n_in,
                              void* d_out, int out_size, void* d_ws, size_t ws_size,
                              hipStream_t stream) {
  const float* x    = (const float*)d_in[0];
  const float* mu   = (const float*)d_in[1];
  const float* rho  = (const float*)d_in[2];
  const float* beta = (const float*)d_in[3];
  float* out = (float*)d_out;
  float* ws  = (float*)d_ws;

  hipLaunchKernelGGL(k_stats, dim3(32),        dim3(256), 0, stream, mu, rho, ws, out);
  hipLaunchKernelGGL(k_main,  dim3(NBLK_MAIN), dim3(512), 0, stream, x, beta, ws);
  hipLaunchKernelGGL(k_final, dim3(256),       dim3(512), 0, stream, ws, out);
}